// Round 5
// baseline (145.850 us; speedup 1.0000x reference)
//
#include <hip/hip_runtime.h>

// ---------------------------------------------------------------------------
// MemoryCausalSelfAttention for MI355X (gfx950).
// cvt->bf16 ; copy/compress mem segments ; qkv GEMM (128^2 tile, swizzled LDS,
// double-buffered global_load_lds pipeline, fused scatter) ; V transpose ;
// flash attention (XCD-local grid, balanced q-tile pairs, LDS-staged K/V) ;
// proj GEMM -> f32.
// Causal mask over concat axis => only first 1024 keys ever attended.
// ---------------------------------------------------------------------------

using u16    = unsigned short;
using bf16x8 = __attribute__((ext_vector_type(8))) __bf16;
using f32x4  = __attribute__((ext_vector_type(4))) float;
using u16x8  = __attribute__((ext_vector_type(8))) unsigned short;
using u16x4  = __attribute__((ext_vector_type(4))) unsigned short;

__device__ __forceinline__ u16 f2bf(float f) {
    union { float f; unsigned u; } v; v.f = f;
    unsigned r = v.u + 0x7FFFu + ((v.u >> 16) & 1u);   // RNE
    return (u16)(r >> 16);
}

__device__ __forceinline__ void gload16(const void* src, const void* lds_base) {
    __builtin_amdgcn_global_load_lds(
        (const __attribute__((address_space(1))) void*)src,
        (__attribute__((address_space(3))) void*)lds_base, 16, 0, 0);
}

// ---------------------------- elementwise f32->bf16 ------------------------
__global__ void cvt_f32_bf16(const float* __restrict__ src, u16* __restrict__ dst, int n4) {
    int i = blockIdx.x * blockDim.x + threadIdx.x;
    if (i >= n4) return;
    float4 f = reinterpret_cast<const float4*>(src)[i];
    u16x4 o; o[0] = f2bf(f.x); o[1] = f2bf(f.y); o[2] = f2bf(f.z); o[3] = f2bf(f.w);
    reinterpret_cast<u16x4*>(dst)[i] = o;
}

// ------------------- copy mem_k1/k2 (f32) into all_k (bf16) ----------------
__global__ __launch_bounds__(64) void copy_mem_rows(const float* __restrict__ src,
                                                    u16* __restrict__ dst, int L, int ro) {
    int bh = blockIdx.y, t = blockIdx.x, d = threadIdx.x;
    float v = src[((size_t)bh * L + t) * 64 + d];
    dst[((size_t)bh * 1024 + ro + t) * 64 + d] = f2bf(v);
}

// --------- depthwise conv1d(k=2,s=2,pad=1) + LayerNorm(64) -> bf16 ---------
__global__ __launch_bounds__(64) void compress_ln(const float* __restrict__ src,
                                                  const float* __restrict__ w,
                                                  const float* __restrict__ g,
                                                  const float* __restrict__ bta,
                                                  u16* __restrict__ dst, int ro) {
    int bh = blockIdx.y, t = blockIdx.x, d = threadIdx.x;
    const float* seg = src + (size_t)bh * 513 * 64;
    float x0 = (t > 0) ? seg[(size_t)(2 * t - 1) * 64 + d] : 0.f;
    float x1 = seg[(size_t)(2 * t) * 64 + d];
    float y = w[2 * d] * x0 + w[2 * d + 1] * x1;
    float s = y;
    #pragma unroll
    for (int o = 32; o; o >>= 1) s += __shfl_xor(s, o);
    float mu = s * (1.f / 64.f);
    float dv = y - mu;
    float s2 = dv * dv;
    #pragma unroll
    for (int o = 32; o; o >>= 1) s2 += __shfl_xor(s2, o);
    float var = s2 * (1.f / 64.f);
    float out = dv * rsqrtf(var + 1e-5f) * g[d] + bta[d];
    dst[((size_t)bh * 1024 + ro + t) * 64 + d] = f2bf(out);
}

// ----------------- V transpose: [bh][1024][64] -> [bh][64][1024] -----------
__global__ __launch_bounds__(256) void transpose_v(const u16* __restrict__ src,
                                                   u16* __restrict__ dst) {
    __shared__ u16 tile[64][66];
    const int bh = blockIdx.y, t0 = blockIdx.x * 64;
    const int tid = threadIdx.x;
    #pragma unroll
    for (int i = 0; i < 2; ++i) {
        int p = tid + i * 256;
        int tr = p >> 3, dc = (p & 7) * 8;
        *(u16x8*)&tile[tr][dc] = *(const u16x8*)&src[((size_t)bh * 1024 + t0 + tr) * 64 + dc];
    }
    __syncthreads();
    #pragma unroll
    for (int i = 0; i < 2; ++i) {
        int p = tid + i * 256;
        int d = p >> 3, tc = (p & 7) * 8;
        u16x8 v;
        #pragma unroll
        for (int e = 0; e < 8; ++e) v[e] = tile[tc + e][d];
        *(u16x8*)&dst[((size_t)bh * 64 + d) * 1024 + t0 + tc] = v;
    }
}

// --------------- GEMM (swizzled + 2-phase pipeline): C = A*W^T + b ---------
// A [M][K] bf16, W [N][K] bf16. 128x128 tile, BK=64, 4 waves, 4x4 frags/wave.
// LDS double-buffered; tile t+1 staged via global_load_lds while computing t;
// ONE barrier per K-step. XOR swizzle (row&7)<<4 on byte col, applied to the
// global SOURCE at stage time and to the ds_read address (rule 21) -> 16-way
// bank conflict becomes free 2-way.
// mode 0: out f32 [M][N]. mode 1 (qkv): scatter q (x0.125) / k,v (t<381).
__global__ __launch_bounds__(256) void gemm128(const u16* __restrict__ A,
                                               const u16* __restrict__ Bw,
                                               const float* __restrict__ bias,
                                               int K, int N, int mode,
                                               float* __restrict__ outF,
                                               u16* __restrict__ q_buf,
                                               u16* __restrict__ all_k,
                                               u16* __restrict__ all_v) {
    __shared__ __align__(16) u16 Al[2][128 * 64];
    __shared__ __align__(16) u16 Bl[2][128 * 64];
    const int tid = threadIdx.x;
    const int wv = tid >> 6, lane = tid & 63;
    const int lg = lane >> 4, lr = lane & 15;
    const int wr = (wv >> 1) * 64, wc = (wv & 1) * 64;
    const int m0 = blockIdx.x * 128, n0 = blockIdx.y * 128;
    f32x4 acc[4][4] = {};
    const int ob0 = wv * 4096;                 // wave's 4KB slice of each 16KB tile
    int srow[4], scol[4];                      // staging: row + pre-swizzled col
    #pragma unroll
    for (int c = 0; c < 4; ++c) {
        int o = ob0 + c * 1024 + lane * 16;    // linear dest byte offset
        int r = o >> 7;                        // LDS row (128B pitch)
        srow[c] = r;
        scol[c] = (o & 127) ^ ((r & 7) << 4);  // source col pre-XORed
    }
    const int nk = K >> 6;
    // prologue: stage tile 0 into buf 0
    #pragma unroll
    for (int c = 0; c < 4; ++c) {
        int ob = ob0 + c * 1024;
        gload16((const char*)A  + (((size_t)(m0 + srow[c]) * K) << 1) + scol[c], (char*)&Al[0][0] + ob);
        gload16((const char*)Bw + (((size_t)(n0 + srow[c]) * K) << 1) + scol[c], (char*)&Bl[0][0] + ob);
    }
    __syncthreads();                           // drains vmcnt(0): tile 0 ready
    int cur = 0;
    for (int kt = 0; kt < nk; ++kt) {
        if (kt + 1 < nk) {                     // stage next tile into cur^1
            const size_t ko = (size_t)(kt + 1) << 6;
            #pragma unroll
            for (int c = 0; c < 4; ++c) {
                int ob = ob0 + c * 1024;
                gload16((const char*)A  + (((size_t)(m0 + srow[c]) * K + ko) << 1) + scol[c],
                        (char*)&Al[cur ^ 1][0] + ob);
                gload16((const char*)Bw + (((size_t)(n0 + srow[c]) * K + ko) << 1) + scol[c],
                        (char*)&Bl[cur ^ 1][0] + ob);
            }
        }
        const char* At = (const char*)&Al[cur][0];
        const char* Bt = (const char*)&Bl[cur][0];
        #pragma unroll
        for (int dh = 0; dh < 2; ++dh) {
            bf16x8 af[4], bq[4];
            #pragma unroll
            for (int mi = 0; mi < 4; ++mi) {
                int row = wr + mi * 16 + lr;
                af[mi] = *(const bf16x8*)(At + row * 128 + ((dh * 64 + lg * 16) ^ ((row & 7) << 4)));
            }
            #pragma unroll
            for (int ni = 0; ni < 4; ++ni) {
                int row = wc + ni * 16 + lr;
                bq[ni] = *(const bf16x8*)(Bt + row * 128 + ((dh * 64 + lg * 16) ^ ((row & 7) << 4)));
            }
            __builtin_amdgcn_s_setprio(1);
            #pragma unroll
            for (int mi = 0; mi < 4; ++mi)
                #pragma unroll
                for (int ni = 0; ni < 4; ++ni)
                    acc[mi][ni] = __builtin_amdgcn_mfma_f32_16x16x32_bf16(af[mi], bq[ni], acc[mi][ni], 0, 0, 0);
            __builtin_amdgcn_s_setprio(0);
        }
        __syncthreads();                       // drains vmcnt(0): next tile landed,
        cur ^= 1;                              // and all waves done reading cur
    }
    #pragma unroll
    for (int mi = 0; mi < 4; ++mi)
        #pragma unroll
        for (int ni = 0; ni < 4; ++ni)
            #pragma unroll
            for (int r = 0; r < 4; ++r) {
                int mm = m0 + wr + mi * 16 + lg * 4 + r;   // D row = (lane>>4)*4+reg
                int nn = n0 + wc + ni * 16 + lr;           // D col = lane&15
                float v = acc[mi][ni][r] + bias[nn];
                if (mode == 0) {
                    outF[(size_t)mm * N + nn] = v;
                } else {
                    int which = nn >> 10, c = nn & 1023, h = c >> 6, d = c & 63;
                    int b = mm >> 10, t = mm & 1023;
                    int bh = b * 16 + h;
                    if (which == 0) {
                        q_buf[((size_t)bh * 1024 + t) * 64 + d] = f2bf(v * 0.125f);
                    } else if (t < 381) {                  // concat col 643+t <= 1023
                        u16* dst = (which == 1) ? all_k : all_v;
                        dst[((size_t)bh * 1024 + 643 + t) * 64 + d] = f2bf(v);
                    }
                }
            }
}

// ------------------------------- attention ---------------------------------
// grid (x=bh 64, y=pair 8): linear id % 8 == bh % 8 -> all 8 blocks of a bh
// land on one XCD -> K/V stay L2-resident (2MB/XCD). Each block processes
// q-tiles {pair, 15-pair}: 17 kv-tiles total, perfectly balanced.
// K and V^T tiles staged ONCE per block into double-buffered swizzled LDS
// (global_load_lds, pre-swizzled source per rule 21) and shared by 4 waves.
__global__ __launch_bounds__(256) void attn_kernel(const u16* __restrict__ Q,
                                                   const u16* __restrict__ Kc,
                                                   const u16* __restrict__ VT,
                                                   u16* __restrict__ Y) {
    __shared__ __align__(16) u16 Kl[2][4096];      // [64 keys][64 d], swizzled, 8KB x2
    __shared__ __align__(16) u16 Vl[2][4096];      // [64 d][64 keys], swizzled, 8KB x2
    __shared__ __align__(16) u16 P_w[4][16 * 64];  // per-wave P/O buffer, swizzled
    const int tid = threadIdx.x;
    const int lane = tid & 63;
    const int w = tid >> 6;
    const int lg = lane >> 4, lr = lane & 15;
    const int bh = blockIdx.x;
    const int pair = blockIdx.y;
    const u16* Kb = Kc + (size_t)bh * 65536;
    const u16* Vb = VT + (size_t)bh * 65536;
    char* Pbase = (char*)&P_w[w][0];
    const int xorq = (lr & 7) << 4;                // byte-XOR, involution (G4)

    const int r0 = tid >> 3,         c0 = ((tid & 7) * 16) ^ ((r0 & 7) << 4);
    const int r1 = (tid + 256) >> 3, c1 = ((tid & 7) * 16) ^ ((r1 & 7) << 4);
    const int dst0 = w * 1024;

    for (int phase = 0; phase < 2; ++phase) {
        const int qt = phase ? (15 - pair) : pair; // q-tile index (64 q)
        const int q0 = qt * 64;
        const u16* Qb = Q + ((size_t)bh * 1024 + q0 + w * 16) * 64;
        bf16x8 qf0 = *(const bf16x8*)&Qb[lr * 64 + lg * 8];        // B-frag [q][d]
        bf16x8 qf1 = *(const bf16x8*)&Qb[lr * 64 + 32 + lg * 8];
        f32x4 o[4] = {};                                           // O^T[d][q]
        float m = -1e30f, lsum = 0.f;
        const int i_q = q0 + w * 16 + lr;

        {
            const char* Ks = (const char*)Kb;
            gload16(Ks + ((size_t)r0 << 7) + c0, (char*)&Kl[0][0] + dst0);
            gload16(Ks + ((size_t)r1 << 7) + c1, (char*)&Kl[0][0] + 4096 + dst0);
            gload16((const char*)Vb + ((size_t)r0 << 11) + c0, (char*)&Vl[0][0] + dst0);
            gload16((const char*)Vb + ((size_t)r1 << 11) + c1, (char*)&Vl[0][0] + 4096 + dst0);
        }
        __syncthreads();
        int cur = 0;

        for (int kt = 0; kt <= qt; ++kt) {
            if (kt < qt) {                          // stage next tile into cur^1
                const int k0n = (kt + 1) * 64;
                const char* Ks = (const char*)Kb + ((size_t)k0n << 7);
                const char* Vs = (const char*)Vb + ((size_t)k0n << 1);
                char* Kd = (char*)&Kl[cur ^ 1][0];
                char* Vd = (char*)&Vl[cur ^ 1][0];
                gload16(Ks + ((size_t)r0 << 7) + c0, Kd + dst0);
                gload16(Ks + ((size_t)r1 << 7) + c1, Kd + 4096 + dst0);
                gload16(Vs + ((size_t)r0 << 11) + c0, Vd + dst0);
                gload16(Vs + ((size_t)r1 << 11) + c1, Vd + 4096 + dst0);
            }
            const char* Kt = (const char*)&Kl[cur][0];
            const char* Vt = (const char*)&Vl[cur][0];
            f32x4 st[4] = {};
            __builtin_amdgcn_s_setprio(1);
            #pragma unroll
            for (int hh = 0; hh < 4; ++hh) {        // S^T[key][q], A = K rows
                const char* Kr = Kt + (size_t)(hh * 16 + lr) * 128;
                bf16x8 kf0 = *(const bf16x8*)(Kr + ((lg * 16) ^ xorq));
                bf16x8 kf1 = *(const bf16x8*)(Kr + ((64 + lg * 16) ^ xorq));
                st[hh] = __builtin_amdgcn_mfma_f32_16x16x32_bf16(kf0, qf0, st[hh], 0, 0, 0);
                st[hh] = __builtin_amdgcn_mfma_f32_16x16x32_bf16(kf1, qf1, st[hh], 0, 0, 0);
            }
            __builtin_amdgcn_s_setprio(0);
            const int k0 = kt * 64;
            float sv[16];
            float tmax = -1e30f;
            if (kt == qt) {                         // diagonal tile: mask j<=i
                #pragma unroll
                for (int hh = 0; hh < 4; ++hh)
                    #pragma unroll
                    for (int r = 0; r < 4; ++r) {
                        int j = k0 + hh * 16 + lg * 4 + r;
                        float s = (j <= i_q) ? st[hh][r] : -1e30f;
                        sv[hh * 4 + r] = s;
                        tmax = fmaxf(tmax, s);
                    }
            } else {
                #pragma unroll
                for (int hh = 0; hh < 4; ++hh)
                    #pragma unroll
                    for (int r = 0; r < 4; ++r) {
                        float s = st[hh][r];
                        sv[hh * 4 + r] = s;
                        tmax = fmaxf(tmax, s);
                    }
            }
            tmax = fmaxf(tmax, __shfl_xor(tmax, 16));
            tmax = fmaxf(tmax, __shfl_xor(tmax, 32));
            if (!__all(tmax - m <= 8.f)) {          // defer-max (T13, THR=8)
                float mnew = fmaxf(m, tmax);
                float alpha = __expf(m - mnew);
                #pragma unroll
                for (int c = 0; c < 4; ++c) {
                    o[c][0] *= alpha; o[c][1] *= alpha; o[c][2] *= alpha; o[c][3] *= alpha;
                }
                lsum *= alpha;
                m = mnew;
            }
            float psum = 0.f;
            #pragma unroll
            for (int hh = 0; hh < 4; ++hh) {        // P[q=lr][key], swizzled write
                u16x4 pk;
                #pragma unroll
                for (int r = 0; r < 4; ++r) {
                    float p = __expf(sv[hh * 4 + r] - m);
                    psum += p;
                    pk[r] = f2bf(p);
                }
                *(u16x4*)(Pbase + lr * 128 + ((hh * 32 + lg * 8) ^ xorq)) = pk;
            }
            psum += __shfl_xor(psum, 16);
            psum += __shfl_xor(psum, 32);
            lsum += psum;
            asm volatile("s_waitcnt lgkmcnt(0)" ::: "memory");   // P visible (wave-local)
            __builtin_amdgcn_sched_barrier(0);
            #pragma unroll
            for (int ks = 0; ks < 2; ++ks) {
                bf16x8 pf = *(const bf16x8*)(Pbase + lr * 128 + ((ks * 64 + lg * 16) ^ xorq));
                __builtin_amdgcn_s_setprio(1);
                #pragma unroll
                for (int c = 0; c < 4; ++c) {       // A-frag V^T rows c*16+lr
                    const char* Vr = Vt + (size_t)(c * 16 + lr) * 128;
                    bf16x8 vf = *(const bf16x8*)(Vr + ((ks * 64 + lg * 16) ^ xorq));
                    o[c] = __builtin_amdgcn_mfma_f32_16x16x32_bf16(vf, pf, o[c], 0, 0, 0);
                }
                __builtin_amdgcn_s_setprio(0);
            }
            __syncthreads();                        // all waves done with cur;
            cur ^= 1;                               // staged next tile landed
        }
        float inv = 1.0f / lsum;
        #pragma unroll
        for (int c = 0; c < 4; ++c) {               // O[q=lr][d], swizzled write
            u16x4 ov;
            #pragma unroll
            for (int r = 0; r < 4; ++r) ov[r] = f2bf(o[c][r] * inv);
            *(u16x4*)(Pbase + lr * 128 + (((c * 16 + lg * 4) * 2) ^ xorq)) = ov;
        }
        asm volatile("s_waitcnt lgkmcnt(0)" ::: "memory");
        __builtin_amdgcn_sched_barrier(0);
        const int b = bh >> 4, h = bh & 15;
        const int qr = lane >> 2, dseg = (lane & 3) * 16;
        const int xorr = (qr & 7) << 4;
        size_t g = ((size_t)(b * 1024 + q0 + w * 16 + qr)) * 1024 + h * 64 + dseg;
        *(u16x8*)&Y[g]     = *(const u16x8*)(Pbase + qr * 128 + ((dseg * 2) ^ xorr));
        *(u16x8*)&Y[g + 8] = *(const u16x8*)(Pbase + qr * 128 + ((dseg * 2 + 16) ^ xorr));
    }
}

// ---------------------------------------------------------------------------
extern "C" void kernel_launch(void* const* d_in, const int* in_sizes, int n_in,
                              void* d_out, int out_size, void* d_ws, size_t ws_size,
                              hipStream_t stream) {
    const float* x            = (const float*)d_in[0];
    const float* mem_k1       = (const float*)d_in[1];
    const float* mem_v1       = (const float*)d_in[2];
    const float* mem_k2       = (const float*)d_in[3];
    const float* mem_v2       = (const float*)d_in[4];
    const float* mem_k3       = (const float*)d_in[5];
    const float* mem_v3       = (const float*)d_in[6];
    const float* c_attn_w     = (const float*)d_in[7];
    const float* c_attn_b     = (const float*)d_in[8];
    const float* c_proj_w     = (const float*)d_in[9];
    const float* c_proj_b     = (const float*)d_in[10];
    const float* compress_k_w = (const float*)d_in[11];
    const float* ln_k_g       = (const float*)d_in[12];
    const float* ln_k_b       = (const float*)d_in[13];
    const float* compress_v_w = (const float*)d_in[14];
    const float* ln_v_g       = (const float*)d_in[15];
    const float* ln_v_b       = (const float*)d_in[16];

    char* ws = (char*)d_ws;
    u16* x_bf   = (u16*)(ws);                     // [4096][1024]   8 MB (dead after qkv)
    u16* all_vT = (u16*)(ws);                     // [64][64][1024] 8 MB (reuses x_bf)
    u16* wq_bf  = (u16*)(ws + (8u << 20));        // [3072][1024]   6 MB
    u16* wp_bf  = (u16*)(ws + (14u << 20));       // [1024][1024]   2 MB
    u16* q_buf  = (u16*)(ws + (16u << 20));       // [64][1024][64] 8 MB
    u16* all_k  = (u16*)(ws + (24u << 20));       // [64][1024][64] 8 MB
    u16* all_v  = (u16*)(ws + (32u << 20));       // [64][1024][64] 8 MB
    u16* att_y  = (u16*)(ws + (40u << 20));       // [4096][1024]   8 MB
    float* out = (float*)d_out;

    cvt_f32_bf16<<<4096, 256, 0, stream>>>(x, x_bf, 1048576);
    cvt_f32_bf16<<<3072, 256, 0, stream>>>(c_attn_w, wq_bf, 786432);
    cvt_f32_bf16<<<1024, 256, 0, stream>>>(c_proj_w, wp_bf, 262144);

    copy_mem_rows<<<dim3(129, 64), 64, 0, stream>>>(mem_k1, all_k, 129, 0);
    copy_mem_rows<<<dim3(129, 64), 64, 0, stream>>>(mem_v1, all_v, 129, 0);
    copy_mem_rows<<<dim3(257, 64), 64, 0, stream>>>(mem_k2, all_k, 257, 129);
    copy_mem_rows<<<dim3(257, 64), 64, 0, stream>>>(mem_v2, all_v, 257, 129);

    compress_ln<<<dim3(257, 64), 64, 0, stream>>>(mem_k3, compress_k_w, ln_k_g, ln_k_b, all_k, 386);
    compress_ln<<<dim3(257, 64), 64, 0, stream>>>(mem_v3, compress_v_w, ln_v_g, ln_v_b, all_v, 386);

    // qkv: M=4096, N=3072, K=1024 -> scatter q/k/v
    gemm128<<<dim3(32, 24), 256, 0, stream>>>(x_bf, wq_bf, c_attn_b, 1024, 3072, 1,
                                              nullptr, q_buf, all_k, all_v);

    transpose_v<<<dim3(16, 64), 256, 0, stream>>>(all_v, all_vT);

    // attention: x = bh (XCD locality), y = q-tile pair (load balance)
    attn_kernel<<<dim3(64, 8), 256, 0, stream>>>(q_buf, all_k, all_vT, att_y);

    // proj: M=4096, N=1024, K=1024 -> f32 out
    gemm128<<<dim3(32, 8), 256, 0, stream>>>(att_y, wp_bf, c_proj_b, 1024, 1024, 0,
                                             out, nullptr, nullptr, nullptr);
}

// Round 6
// 132.979 us; speedup vs baseline: 1.0968x; 1.0968x over previous
//
#include <hip/hip_runtime.h>

// ---------------------------------------------------------------------------
// MemoryCausalSelfAttention for MI355X (gfx950).
// cvt->bf16 ; copy/compress mem segments ; qkv GEMM (128^2 tile, BK=32,
// 32KB double-buffered LDS pipeline, both-sides swizzle, XCD-grouped grid,
// fused scatter) ; V transpose ; flash attention (XCD-local grid, balanced
// q-tile pairs, LDS-staged K/V) ; proj GEMM -> f32.
// Causal mask over concat axis => only first 1024 keys ever attended.
// ---------------------------------------------------------------------------

using u16    = unsigned short;
using bf16x8 = __attribute__((ext_vector_type(8))) __bf16;
using f32x4  = __attribute__((ext_vector_type(4))) float;
using u16x8  = __attribute__((ext_vector_type(8))) unsigned short;
using u16x4  = __attribute__((ext_vector_type(4))) unsigned short;

__device__ __forceinline__ u16 f2bf(float f) {
    union { float f; unsigned u; } v; v.f = f;
    unsigned r = v.u + 0x7FFFu + ((v.u >> 16) & 1u);   // RNE
    return (u16)(r >> 16);
}

__device__ __forceinline__ void gload16(const void* src, const void* lds_base) {
    __builtin_amdgcn_global_load_lds(
        (const __attribute__((address_space(1))) void*)src,
        (__attribute__((address_space(3))) void*)lds_base, 16, 0, 0);
}

// ---------------------------- elementwise f32->bf16 ------------------------
__global__ void cvt_f32_bf16(const float* __restrict__ src, u16* __restrict__ dst, int n4) {
    int i = blockIdx.x * blockDim.x + threadIdx.x;
    if (i >= n4) return;
    float4 f = reinterpret_cast<const float4*>(src)[i];
    u16x4 o; o[0] = f2bf(f.x); o[1] = f2bf(f.y); o[2] = f2bf(f.z); o[3] = f2bf(f.w);
    reinterpret_cast<u16x4*>(dst)[i] = o;
}

// ------------------- copy mem_k1/k2 (f32) into all_k (bf16) ----------------
__global__ __launch_bounds__(64) void copy_mem_rows(const float* __restrict__ src,
                                                    u16* __restrict__ dst, int L, int ro) {
    int bh = blockIdx.y, t = blockIdx.x, d = threadIdx.x;
    float v = src[((size_t)bh * L + t) * 64 + d];
    dst[((size_t)bh * 1024 + ro + t) * 64 + d] = f2bf(v);
}

// --------- depthwise conv1d(k=2,s=2,pad=1) + LayerNorm(64) -> bf16 ---------
__global__ __launch_bounds__(64) void compress_ln(const float* __restrict__ src,
                                                  const float* __restrict__ w,
                                                  const float* __restrict__ g,
                                                  const float* __restrict__ bta,
                                                  u16* __restrict__ dst, int ro) {
    int bh = blockIdx.y, t = blockIdx.x, d = threadIdx.x;
    const float* seg = src + (size_t)bh * 513 * 64;
    float x0 = (t > 0) ? seg[(size_t)(2 * t - 1) * 64 + d] : 0.f;
    float x1 = seg[(size_t)(2 * t) * 64 + d];
    float y = w[2 * d] * x0 + w[2 * d + 1] * x1;
    float s = y;
    #pragma unroll
    for (int o = 32; o; o >>= 1) s += __shfl_xor(s, o);
    float mu = s * (1.f / 64.f);
    float dv = y - mu;
    float s2 = dv * dv;
    #pragma unroll
    for (int o = 32; o; o >>= 1) s2 += __shfl_xor(s2, o);
    float var = s2 * (1.f / 64.f);
    float out = dv * rsqrtf(var + 1e-5f) * g[d] + bta[d];
    dst[((size_t)bh * 1024 + ro + t) * 64 + d] = f2bf(out);
}

// ----------------- V transpose: [bh][1024][64] -> [bh][64][1024] -----------
__global__ __launch_bounds__(256) void transpose_v(const u16* __restrict__ src,
                                                   u16* __restrict__ dst) {
    __shared__ u16 tile[64][66];
    const int bh = blockIdx.y, t0 = blockIdx.x * 64;
    const int tid = threadIdx.x;
    #pragma unroll
    for (int i = 0; i < 2; ++i) {
        int p = tid + i * 256;
        int tr = p >> 3, dc = (p & 7) * 8;
        *(u16x8*)&tile[tr][dc] = *(const u16x8*)&src[((size_t)bh * 1024 + t0 + tr) * 64 + dc];
    }
    __syncthreads();
    #pragma unroll
    for (int i = 0; i < 2; ++i) {
        int p = tid + i * 256;
        int d = p >> 3, tc = (p & 7) * 8;
        u16x8 v;
        #pragma unroll
        for (int e = 0; e < 8; ++e) v[e] = tile[tc + e][d];
        *(u16x8*)&dst[((size_t)bh * 64 + d) * 1024 + t0 + tc] = v;
    }
}

// ------------- GEMM: 128^2 tile, BK=32, 32KB dbuf LDS, swizzled ------------
// A [M][K] bf16, W [N][K] bf16. 4 waves, 4x4 16x16 frags/wave. Per K-step:
// read frags (8 ds_read_b128) -> issue next-tile stage (4 global_load_lds)
// -> 16 MFMA -> one barrier. XOR swizzle X(row)=((row>>1)&3)<<4 applied to
// global SOURCE at stage and to ds_read address (both-sides, rule 21).
// Grid remap: nid=(id&7)*per+(id>>3) groups consecutive n-panels per XCD.
// mode 0: out f32 [M][N]. mode 1 (qkv): scatter q (x0.125) / k,v (t<381).
__global__ __launch_bounds__(256) void gemm128(const u16* __restrict__ A,
                                               const u16* __restrict__ Bw,
                                               const float* __restrict__ bias,
                                               int K, int N, int mode,
                                               float* __restrict__ outF,
                                               u16* __restrict__ q_buf,
                                               u16* __restrict__ all_k,
                                               u16* __restrict__ all_v) {
    __shared__ __align__(16) u16 Al[2][128 * 32];   // 8KB per buf
    __shared__ __align__(16) u16 Bl[2][128 * 32];
    const int tid = threadIdx.x;
    const int wv = tid >> 6, lane = tid & 63;
    const int lg = lane >> 4, lr = lane & 15;
    const int wr = (wv >> 1) * 64, wc = (wv & 1) * 64;
    // XCD grouping: blocks with id%8==x (one XCD) get consecutive nid range
    const int id = blockIdx.x + blockIdx.y * gridDim.x;
    const int per = (gridDim.x * gridDim.y) >> 3;      // grids are %8==0
    const int nid = (id & 7) * per + (id >> 3);
    const int m0 = (nid % gridDim.x) * 128, n0 = (nid / gridDim.x) * 128;
    f32x4 acc[4][4] = {};
    // staging: 512 x 16B segs per 8KB tile; seg s -> row s>>2, colseg s&3.
    // source col pre-XORed with X(row) so swizzled reads see correct data.
    const int sr0 = tid >> 2,         sc0 = (((tid & 3) << 4)) ^ (((sr0 >> 1) & 3) << 4);
    const int sr1 = (tid + 256) >> 2, sc1 = (((tid & 3) << 4)) ^ (((sr1 >> 1) & 3) << 4);
    const int dA0 = wv * 1024;                          // + lane*16 implicit
    const int dA1 = 4096 + wv * 1024;
    const int nk = K >> 5;
    // prologue: stage tile 0 into buf 0
    gload16((const char*)A  + (((size_t)(m0 + sr0) * K) << 1) + sc0, (char*)&Al[0][0] + dA0);
    gload16((const char*)A  + (((size_t)(m0 + sr1) * K) << 1) + sc1, (char*)&Al[0][0] + dA1);
    gload16((const char*)Bw + (((size_t)(n0 + sr0) * K) << 1) + sc0, (char*)&Bl[0][0] + dA0);
    gload16((const char*)Bw + (((size_t)(n0 + sr1) * K) << 1) + sc1, (char*)&Bl[0][0] + dA1);
    __syncthreads();                                    // tile 0 ready
    int cur = 0;
    for (int kt = 0; kt < nk; ++kt) {
        const char* At = (const char*)&Al[cur][0];
        const char* Bt = (const char*)&Bl[cur][0];
        bf16x8 af[4], bq[4];
        #pragma unroll
        for (int mi = 0; mi < 4; ++mi) {                // frag reads FIRST
            int row = wr + mi * 16 + lr;
            af[mi] = *(const bf16x8*)(At + row * 64 + ((lg << 4) ^ (((row >> 1) & 3) << 4)));
        }
        #pragma unroll
        for (int ni = 0; ni < 4; ++ni) {
            int row = wc + ni * 16 + lr;
            bq[ni] = *(const bf16x8*)(Bt + row * 64 + ((lg << 4) ^ (((row >> 1) & 3) << 4)));
        }
        if (kt + 1 < nk) {                              // then issue next stage
            const size_t ko = (size_t)(kt + 1) << 5;
            char* Ad = (char*)&Al[cur ^ 1][0];
            char* Bd = (char*)&Bl[cur ^ 1][0];
            gload16((const char*)A  + (((size_t)(m0 + sr0) * K + ko) << 1) + sc0, Ad + dA0);
            gload16((const char*)A  + (((size_t)(m0 + sr1) * K + ko) << 1) + sc1, Ad + dA1);
            gload16((const char*)Bw + (((size_t)(n0 + sr0) * K + ko) << 1) + sc0, Bd + dA0);
            gload16((const char*)Bw + (((size_t)(n0 + sr1) * K + ko) << 1) + sc1, Bd + dA1);
        }
        __builtin_amdgcn_s_setprio(1);
        #pragma unroll
        for (int mi = 0; mi < 4; ++mi)
            #pragma unroll
            for (int ni = 0; ni < 4; ++ni)
                acc[mi][ni] = __builtin_amdgcn_mfma_f32_16x16x32_bf16(af[mi], bq[ni], acc[mi][ni], 0, 0, 0);
        __builtin_amdgcn_s_setprio(0);
        __syncthreads();                                // next tile landed; all
        cur ^= 1;                                       // waves done with cur
    }
    #pragma unroll
    for (int mi = 0; mi < 4; ++mi)
        #pragma unroll
        for (int ni = 0; ni < 4; ++ni)
            #pragma unroll
            for (int r = 0; r < 4; ++r) {
                int mm = m0 + wr + mi * 16 + lg * 4 + r;   // D row = (lane>>4)*4+reg
                int nn = n0 + wc + ni * 16 + lr;           // D col = lane&15
                float v = acc[mi][ni][r] + bias[nn];
                if (mode == 0) {
                    outF[(size_t)mm * N + nn] = v;
                } else {
                    int which = nn >> 10, c = nn & 1023, h = c >> 6, d = c & 63;
                    int b = mm >> 10, t = mm & 1023;
                    int bh = b * 16 + h;
                    if (which == 0) {
                        q_buf[((size_t)bh * 1024 + t) * 64 + d] = f2bf(v * 0.125f);
                    } else if (t < 381) {                  // concat col 643+t <= 1023
                        u16* dst = (which == 1) ? all_k : all_v;
                        dst[((size_t)bh * 1024 + 643 + t) * 64 + d] = f2bf(v);
                    }
                }
            }
}

// ------------------------------- attention ---------------------------------
// grid (x=bh 64, y=pair 8): linear id % 8 == bh % 8 -> all 8 blocks of a bh
// land on one XCD -> K/V stay L2-resident (2MB/XCD). Each block processes
// q-tiles {pair, 15-pair}: 17 kv-tiles total, perfectly balanced.
// K and V^T tiles staged ONCE per block into double-buffered swizzled LDS
// (global_load_lds, pre-swizzled source per rule 21) and shared by 4 waves.
__global__ __launch_bounds__(256) void attn_kernel(const u16* __restrict__ Q,
                                                   const u16* __restrict__ Kc,
                                                   const u16* __restrict__ VT,
                                                   u16* __restrict__ Y) {
    __shared__ __align__(16) u16 Kl[2][4096];      // [64 keys][64 d], swizzled, 8KB x2
    __shared__ __align__(16) u16 Vl[2][4096];      // [64 d][64 keys], swizzled, 8KB x2
    __shared__ __align__(16) u16 P_w[4][16 * 64];  // per-wave P/O buffer, swizzled
    const int tid = threadIdx.x;
    const int lane = tid & 63;
    const int w = tid >> 6;
    const int lg = lane >> 4, lr = lane & 15;
    const int bh = blockIdx.x;
    const int pair = blockIdx.y;
    const u16* Kb = Kc + (size_t)bh * 65536;
    const u16* Vb = VT + (size_t)bh * 65536;
    char* Pbase = (char*)&P_w[w][0];
    const int xorq = (lr & 7) << 4;                // byte-XOR, involution (G4)

    const int r0 = tid >> 3,         c0 = ((tid & 7) * 16) ^ ((r0 & 7) << 4);
    const int r1 = (tid + 256) >> 3, c1 = ((tid & 7) * 16) ^ ((r1 & 7) << 4);
    const int dst0 = w * 1024;

    for (int phase = 0; phase < 2; ++phase) {
        const int qt = phase ? (15 - pair) : pair; // q-tile index (64 q)
        const int q0 = qt * 64;
        const u16* Qb = Q + ((size_t)bh * 1024 + q0 + w * 16) * 64;
        bf16x8 qf0 = *(const bf16x8*)&Qb[lr * 64 + lg * 8];        // B-frag [q][d]
        bf16x8 qf1 = *(const bf16x8*)&Qb[lr * 64 + 32 + lg * 8];
        f32x4 o[4] = {};                                           // O^T[d][q]
        float m = -1e30f, lsum = 0.f;
        const int i_q = q0 + w * 16 + lr;

        {
            const char* Ks = (const char*)Kb;
            gload16(Ks + ((size_t)r0 << 7) + c0, (char*)&Kl[0][0] + dst0);
            gload16(Ks + ((size_t)r1 << 7) + c1, (char*)&Kl[0][0] + 4096 + dst0);
            gload16((const char*)Vb + ((size_t)r0 << 11) + c0, (char*)&Vl[0][0] + dst0);
            gload16((const char*)Vb + ((size_t)r1 << 11) + c1, (char*)&Vl[0][0] + 4096 + dst0);
        }
        __syncthreads();
        int cur = 0;

        for (int kt = 0; kt <= qt; ++kt) {
            if (kt < qt) {                          // stage next tile into cur^1
                const int k0n = (kt + 1) * 64;
                const char* Ks = (const char*)Kb + ((size_t)k0n << 7);
                const char* Vs = (const char*)Vb + ((size_t)k0n << 1);
                char* Kd = (char*)&Kl[cur ^ 1][0];
                char* Vd = (char*)&Vl[cur ^ 1][0];
                gload16(Ks + ((size_t)r0 << 7) + c0, Kd + dst0);
                gload16(Ks + ((size_t)r1 << 7) + c1, Kd + 4096 + dst0);
                gload16(Vs + ((size_t)r0 << 11) + c0, Vd + dst0);
                gload16(Vs + ((size_t)r1 << 11) + c1, Vd + 4096 + dst0);
            }
            const char* Kt = (const char*)&Kl[cur][0];
            const char* Vt = (const char*)&Vl[cur][0];
            f32x4 st[4] = {};
            __builtin_amdgcn_s_setprio(1);
            #pragma unroll
            for (int hh = 0; hh < 4; ++hh) {        // S^T[key][q], A = K rows
                const char* Kr = Kt + (size_t)(hh * 16 + lr) * 128;
                bf16x8 kf0 = *(const bf16x8*)(Kr + ((lg * 16) ^ xorq));
                bf16x8 kf1 = *(const bf16x8*)(Kr + ((64 + lg * 16) ^ xorq));
                st[hh] = __builtin_amdgcn_mfma_f32_16x16x32_bf16(kf0, qf0, st[hh], 0, 0, 0);
                st[hh] = __builtin_amdgcn_mfma_f32_16x16x32_bf16(kf1, qf1, st[hh], 0, 0, 0);
            }
            __builtin_amdgcn_s_setprio(0);
            const int k0 = kt * 64;
            float sv[16];
            float tmax = -1e30f;
            if (kt == qt) {                         // diagonal tile: mask j<=i
                #pragma unroll
                for (int hh = 0; hh < 4; ++hh)
                    #pragma unroll
                    for (int r = 0; r < 4; ++r) {
                        int j = k0 + hh * 16 + lg * 4 + r;
                        float s = (j <= i_q) ? st[hh][r] : -1e30f;
                        sv[hh * 4 + r] = s;
                        tmax = fmaxf(tmax, s);
                    }
            } else {
                #pragma unroll
                for (int hh = 0; hh < 4; ++hh)
                    #pragma unroll
                    for (int r = 0; r < 4; ++r) {
                        float s = st[hh][r];
                        sv[hh * 4 + r] = s;
                        tmax = fmaxf(tmax, s);
                    }
            }
            tmax = fmaxf(tmax, __shfl_xor(tmax, 16));
            tmax = fmaxf(tmax, __shfl_xor(tmax, 32));
            if (!__all(tmax - m <= 8.f)) {          // defer-max (T13, THR=8)
                float mnew = fmaxf(m, tmax);
                float alpha = __expf(m - mnew);
                #pragma unroll
                for (int c = 0; c < 4; ++c) {
                    o[c][0] *= alpha; o[c][1] *= alpha; o[c][2] *= alpha; o[c][3] *= alpha;
                }
                lsum *= alpha;
                m = mnew;
            }
            float psum = 0.f;
            #pragma unroll
            for (int hh = 0; hh < 4; ++hh) {        // P[q=lr][key], swizzled write
                u16x4 pk;
                #pragma unroll
                for (int r = 0; r < 4; ++r) {
                    float p = __expf(sv[hh * 4 + r] - m);
                    psum += p;
                    pk[r] = f2bf(p);
                }
                *(u16x4*)(Pbase + lr * 128 + ((hh * 32 + lg * 8) ^ xorq)) = pk;
            }
            psum += __shfl_xor(psum, 16);
            psum += __shfl_xor(psum, 32);
            lsum += psum;
            asm volatile("s_waitcnt lgkmcnt(0)" ::: "memory");   // P visible (wave-local)
            __builtin_amdgcn_sched_barrier(0);
            #pragma unroll
            for (int ks = 0; ks < 2; ++ks) {
                bf16x8 pf = *(const bf16x8*)(Pbase + lr * 128 + ((ks * 64 + lg * 16) ^ xorq));
                __builtin_amdgcn_s_setprio(1);
                #pragma unroll
                for (int c = 0; c < 4; ++c) {       // A-frag V^T rows c*16+lr
                    const char* Vr = Vt + (size_t)(c * 16 + lr) * 128;
                    bf16x8 vf = *(const bf16x8*)(Vr + ((ks * 64 + lg * 16) ^ xorq));
                    o[c] = __builtin_amdgcn_mfma_f32_16x16x32_bf16(vf, pf, o[c], 0, 0, 0);
                }
                __builtin_amdgcn_s_setprio(0);
            }
            __syncthreads();                        // all waves done with cur;
            cur ^= 1;                               // staged next tile landed
        }
        float inv = 1.0f / lsum;
        #pragma unroll
        for (int c = 0; c < 4; ++c) {               // O[q=lr][d], swizzled write
            u16x4 ov;
            #pragma unroll
            for (int r = 0; r < 4; ++r) ov[r] = f2bf(o[c][r] * inv);
            *(u16x4*)(Pbase + lr * 128 + (((c * 16 + lg * 4) * 2) ^ xorq)) = ov;
        }
        asm volatile("s_waitcnt lgkmcnt(0)" ::: "memory");
        __builtin_amdgcn_sched_barrier(0);
        const int b = bh >> 4, h = bh & 15;
        const int qr = lane >> 2, dseg = (lane & 3) * 16;
        const int xorr = (qr & 7) << 4;
        size_t g = ((size_t)(b * 1024 + q0 + w * 16 + qr)) * 1024 + h * 64 + dseg;
        *(u16x8*)&Y[g]     = *(const u16x8*)(Pbase + qr * 128 + ((dseg * 2) ^ xorr));
        *(u16x8*)&Y[g + 8] = *(const u16x8*)(Pbase + qr * 128 + ((dseg * 2 + 16) ^ xorr));
    }
}

// ---------------------------------------------------------------------------
extern "C" void kernel_launch(void* const* d_in, const int* in_sizes, int n_in,
                              void* d_out, int out_size, void* d_ws, size_t ws_size,
                              hipStream_t stream) {
    const float* x            = (const float*)d_in[0];
    const float* mem_k1       = (const float*)d_in[1];
    const float* mem_v1       = (const float*)d_in[2];
    const float* mem_k2       = (const float*)d_in[3];
    const float* mem_v2       = (const float*)d_in[4];
    const float* mem_k3       = (const float*)d_in[5];
    const float* mem_v3       = (const float*)d_in[6];
    const float* c_attn_w     = (const float*)d_in[7];
    const float* c_attn_b     = (const float*)d_in[8];
    const float* c_proj_w     = (const float*)d_in[9];
    const float* c_proj_b     = (const float*)d_in[10];
    const float* compress_k_w = (const float*)d_in[11];
    const float* ln_k_g       = (const float*)d_in[12];
    const float* ln_k_b       = (const float*)d_in[13];
    const float* compress_v_w = (const float*)d_in[14];
    const float* ln_v_g       = (const float*)d_in[15];
    const float* ln_v_b       = (const float*)d_in[16];

    char* ws = (char*)d_ws;
    u16* x_bf   = (u16*)(ws);                     // [4096][1024]   8 MB (dead after qkv)
    u16* all_vT = (u16*)(ws);                     // [64][64][1024] 8 MB (reuses x_bf)
    u16* wq_bf  = (u16*)(ws + (8u << 20));        // [3072][1024]   6 MB
    u16* wp_bf  = (u16*)(ws + (14u << 20));       // [1024][1024]   2 MB
    u16* q_buf  = (u16*)(ws + (16u << 20));       // [64][1024][64] 8 MB
    u16* all_k  = (u16*)(ws + (24u << 20));       // [64][1024][64] 8 MB
    u16* all_v  = (u16*)(ws + (32u << 20));       // [64][1024][64] 8 MB
    u16* att_y  = (u16*)(ws + (40u << 20));       // [4096][1024]   8 MB
    float* out = (float*)d_out;

    cvt_f32_bf16<<<4096, 256, 0, stream>>>(x, x_bf, 1048576);
    cvt_f32_bf16<<<3072, 256, 0, stream>>>(c_attn_w, wq_bf, 786432);
    cvt_f32_bf16<<<1024, 256, 0, stream>>>(c_proj_w, wp_bf, 262144);

    copy_mem_rows<<<dim3(129, 64), 64, 0, stream>>>(mem_k1, all_k, 129, 0);
    copy_mem_rows<<<dim3(129, 64), 64, 0, stream>>>(mem_v1, all_v, 129, 0);
    copy_mem_rows<<<dim3(257, 64), 64, 0, stream>>>(mem_k2, all_k, 257, 129);
    copy_mem_rows<<<dim3(257, 64), 64, 0, stream>>>(mem_v2, all_v, 257, 129);

    compress_ln<<<dim3(257, 64), 64, 0, stream>>>(mem_k3, compress_k_w, ln_k_g, ln_k_b, all_k, 386);
    compress_ln<<<dim3(257, 64), 64, 0, stream>>>(mem_v3, compress_v_w, ln_v_g, ln_v_b, all_v, 386);

    // qkv: M=4096, N=3072, K=1024 -> scatter q/k/v
    gemm128<<<dim3(32, 24), 256, 0, stream>>>(x_bf, wq_bf, c_attn_b, 1024, 3072, 1,
                                              nullptr, q_buf, all_k, all_v);

    transpose_v<<<dim3(16, 64), 256, 0, stream>>>(all_v, all_vT);

    // attention: x = bh (XCD locality), y = q-tile pair (load balance)
    attn_kernel<<<dim3(64, 8), 256, 0, stream>>>(q_buf, all_k, all_vT, att_y);

    // proj: M=4096, N=1024, K=1024 -> f32 out
    gemm128<<<dim3(32, 8), 256, 0, stream>>>(att_y, wp_bf, c_proj_b, 1024, 1024, 0,
                                             out, nullptr, nullptr, nullptr);
}